// Round 1
// baseline (357.771 us; speedup 1.0000x reference)
//
#include <hip/hip_runtime.h>
#include <hip/hip_bf16.h>

typedef unsigned short u16;
typedef unsigned int u32;
typedef float floatx4 __attribute__((ext_vector_type(4)));
typedef __bf16 bf16x8 __attribute__((ext_vector_type(8)));
typedef u16 ushort4v __attribute__((ext_vector_type(4)));
typedef u16 ushort8v __attribute__((ext_vector_type(8)));

#define DEVI static __device__ __forceinline__

DEVI u16 f2bf(float f) {
    u32 u = __builtin_bit_cast(u32, f);
    u += 0x7fffu + ((u >> 16) & 1u);   // round-to-nearest-even
    return (u16)(u >> 16);
}
DEVI float bf2f(u16 h) { return __builtin_bit_cast(float, (u32)h << 16); }

DEVI float fexp2(float x) { return __builtin_amdgcn_exp2f(x); }  // v_exp_f32

// async global->LDS, 16B per lane. dst must be wave-uniform base; HW adds lane*16.
DEVI void async_cp16(const u16* g, u16* l) {
    __builtin_amdgcn_global_load_lds((const __attribute__((address_space(1))) u32*)g,
                                     (__attribute__((address_space(3))) u32*)l, 16, 0, 0);
}

// ---------------------------------------------------------------------------
// GEMM: C[M,N] = A[M,K](bf16) @ W[N,K](bf16)^T, double-buffered one-barrier
// K-loop, async global_load_lds staging with XOR swizzle.
// XSWZ: XCD m-band block swizzle. NSPLIT>1: split-K partials to o0..o3.
// ---------------------------------------------------------------------------
template<int BM, int BN, int RW, int CW, bool QKV3, int NSPLIT, bool XSWZ,
         bool BIAS, bool RELU, bool RESID, bool OBF16>
__global__ __launch_bounds__(256) void gemm_nt(
    const u16* __restrict__ A,
    const u16* __restrict__ W0, const u16* __restrict__ W1, const u16* __restrict__ W2,
    const float* __restrict__ bias, const float* __restrict__ resid,
    void* __restrict__ o0, void* __restrict__ o1, void* __restrict__ o2,
    void* __restrict__ o3, int K, int lda, int Nper, int NX)
{
    static_assert(RW * CW == 4, "4 waves");
    constexpr int WM = BM / RW, WN = BN / CW;
    constexpr int MI = WM / 16, NI = WN / 16;
    __shared__ __align__(16) u16 As[2][BM * 32];
    __shared__ __align__(16) u16 Bs[2][BN * 32];
    const int tid = threadIdx.x;
    const int w = tid >> 6, lane = tid & 63;
    const int q = lane >> 4, ml = lane & 15;
    const int wr = w / CW, wc = w % CW;
    int bx = blockIdx.x, by = blockIdx.y;
    if (XSWZ) {
        const int gx = gridDim.x, gy = gridDim.y;
        int L = by * gx + bx;
        int xcd = L & 7, s = L >> 3;
        int mb = gy >> 3;              // m-tiles per XCD band (gy % 8 == 0)
        by = xcd * mb + s % mb;
        bx = s / mb;
    }
    const int m0 = by * BM;
    size_t kbase = 0;
    const u16* W = W0;
    void* outp = o0;
    if (NSPLIT > 1) {
        int part = bx / NX; bx -= part * NX; kbase = (size_t)part * K;
        outp = (part == 0) ? o0 : (part == 1 ? o1 : (part == 2 ? o2 : o3));
    }
    int n0 = bx * BN;
    if (QKV3) {
        int sel = n0 / Nper;
        n0 -= sel * Nper;
        W = (sel == 0) ? W0 : (sel == 1 ? W1 : W2);
        outp = (sel == 0) ? o0 : (sel == 1 ? o1 : o2);
    }

    auto stage = [&](int buf, int kt) {
#pragma unroll
        for (int p = 0; p < BM / 64; ++p) {
            int g = p * 256 + tid;
            int r = g >> 2, s = g & 3;
            int c = s ^ ((r >> 1) & 3);
            async_cp16(A + (size_t)(m0 + r) * lda + kbase + kt + c * 8,
                       &As[buf][(p * 256 + w * 64) * 8]);
        }
#pragma unroll
        for (int p = 0; p < BN / 64; ++p) {
            int g = p * 256 + tid;
            int r = g >> 2, s = g & 3;
            int c = s ^ ((r >> 1) & 3);
            async_cp16(W + (size_t)(n0 + r) * lda + kbase + kt + c * 8,
                       &Bs[buf][(p * 256 + w * 64) * 8]);
        }
    };

    const floatx4 fzero = {0.f, 0.f, 0.f, 0.f};
    floatx4 acc[MI][NI];
#pragma unroll
    for (int i = 0; i < MI; ++i)
#pragma unroll
        for (int j = 0; j < NI; ++j) acc[i][j] = fzero;

    stage(0, 0);
    for (int it = 0, kt = 0; kt < K; ++it, kt += 32) {
        __syncthreads();
        if (kt + 32 < K) stage((it + 1) & 1, kt + 32);
        const u16* Asb = As[it & 1];
        const u16* Bsb = Bs[it & 1];
        bf16x8 af[MI], bfr[NI];
#pragma unroll
        for (int i = 0; i < MI; ++i) {
            int rm = wr * WM + i * 16 + ml;
            int s = q ^ ((rm >> 1) & 3);
            af[i] = *(const bf16x8*)&Asb[(rm * 4 + s) * 8];
        }
#pragma unroll
        for (int j = 0; j < NI; ++j) {
            int rn = wc * WN + j * 16 + ml;
            int s = q ^ ((rn >> 1) & 3);
            bfr[j] = *(const bf16x8*)&Bsb[(rn * 4 + s) * 8];
        }
#pragma unroll
        for (int i = 0; i < MI; ++i)
#pragma unroll
            for (int j = 0; j < NI; ++j)
                acc[i][j] = __builtin_amdgcn_mfma_f32_16x16x32_bf16(af[i], bfr[j], acc[i][j], 0, 0, 0);
    }

    // epilogue: C/D layout col=lane&15, row=(lane>>4)*4+reg
#pragma unroll
    for (int j = 0; j < NI; ++j) {
        int gn = n0 + wc * WN + j * 16 + ml;
        float bj = 0.f;
        if (BIAS) bj = bias[gn];
#pragma unroll
        for (int i = 0; i < MI; ++i) {
            int gm0 = m0 + wr * WM + i * 16 + q * 4;
#pragma unroll
            for (int r = 0; r < 4; ++r) {
                size_t idx = (size_t)(gm0 + r) * Nper + gn;
                float v = acc[i][j][r] + bj;
                if (RELU) v = fmaxf(v, 0.f);
                if (RESID) v += resid[idx];
                if (OBF16) ((u16*)outp)[idx] = f2bf(v);
                else       ((float*)outp)[idx] = v;
            }
        }
    }
}

// ---------------------------------------------------------------------------
// Flash attention v8: in-block KV-split for occupancy.
// 256 threads = 4 waves: waves {0,1} do KV rows [0,1024), waves {2,3} do
// [1024,2048); each wave owns 32 queries (qw = w&1 selects query sub-block).
// KV staged in 32-row double-buffered tiles per half (LDS still 32KB/block),
// so 4 blocks/CU x 4 waves = 16 waves/CU = 4 waves/SIMD (2x flash7).
// Partial oacc/lsum combined through LDS in fp32 (no extra kernel/rounding).
// Q,K: [b*2048+s][h*64+d].  Vt: [b*1024+h*64+d][s].
// ---------------------------------------------------------------------------
__global__ __launch_bounds__(256, 4) void flash8(
    const u16* __restrict__ Q, const u16* __restrict__ Kg,
    const u16* __restrict__ Vt, const float* __restrict__ biasv,
    u16* __restrict__ O)
{
    __shared__ __align__(16) u16 Ks[2][2][32 * 64];   // [kvhalf][buf]: 32 s-rows x 64 d
    __shared__ __align__(16) u16 Vs[2][2][64 * 32];   // [kvhalf][buf]: 64 d-rows x 32 s
    const int tid = threadIdx.x;
    const int w = tid >> 6, lane = tid & 63;
    const int qw = w & 1, kv = w >> 1;
    const int q = lane >> 4, ml = lane & 15;
    const int b = blockIdx.y >> 4, h = blockIdx.y & 15;
    const size_t rowQ = (size_t)(b * 2048 + blockIdx.x * 64);
    const float KSC = 0.125f * 1.4426950408889634f;   // /sqrt(64) * log2(e)
    const floatx4 fzero = {0.f, 0.f, 0.f, 0.f};

    bf16x8 qa[2][2];
#pragma unroll
    for (int qg = 0; qg < 2; ++qg)
#pragma unroll
        for (int c = 0; c < 2; ++c)
            qa[qg][c] = *(const bf16x8*)&Q[(rowQ + qw * 32 + qg * 16 + ml) * 1024
                                           + h * 64 + q * 8 + c * 32];

    // stage K/V 32-row tiles for BOTH kv halves (4 x 4KB = 16KB per iter)
    auto stage = [&](int buf, int it) {
        {   // K: 32 rows x 64 d = 256 slots of 16B, 8 chunks/row
            int row = tid >> 3, sl = tid & 7;
            int ch = sl ^ ((row & 3) | (((row >> 3) & 1) << 2));
#pragma unroll
            for (int hf = 0; hf < 2; ++hf) {
                int s0 = hf * 1024 + it * 32;
                async_cp16(Kg + (size_t)(b * 2048 + s0 + row) * 1024 + h * 64 + ch * 8,
                           &Ks[hf][buf][(w * 64) * 8]);
            }
        }
        {   // V: 64 d-rows x 32 s = 256 slots of 16B, 4 chunks/row
            int row = tid >> 2, sl = tid & 3;
            int ch = sl ^ ((row >> 1) & 3);
#pragma unroll
            for (int hf = 0; hf < 2; ++hf) {
                int s0 = hf * 1024 + it * 32;
                async_cp16(Vt + (size_t)(b * 1024 + h * 64 + row) * 2048 + s0 + ch * 8,
                           &Vs[hf][buf][(w * 64) * 8]);
            }
        }
    };

    floatx4 oacc[2][4];
    float lsum[2] = {0.f, 0.f};
#pragma unroll
    for (int qg = 0; qg < 2; ++qg)
#pragma unroll
        for (int d = 0; d < 4; ++d) oacc[qg][d] = fzero;

    const int swk = (ml & 3) | (((ml >> 2) & 1) << 2);
    const int re = ((ml >> 2) << 3) + (ml & 3);   // even K-rows (key relabel)

    stage(0, 0);
    for (int it = 0; it < 32; ++it) {
        __syncthreads();
        if (it + 1 < 32) stage((it + 1) & 1, it + 1);
        const u16* Kb = Ks[kv][it & 1];
        const u16* Vb = Vs[kv][it & 1];
        const int s0 = kv * 1024 + it * 32;

        bf16x8 ke0 = *(const bf16x8*)&Kb[(re + 0) * 64 + ((0 + q) ^ swk) * 8];
        bf16x8 ke1 = *(const bf16x8*)&Kb[(re + 0) * 64 + ((4 + q) ^ swk) * 8];
        bf16x8 ko0 = *(const bf16x8*)&Kb[(re + 4) * 64 + ((0 + q) ^ swk) * 8];
        bf16x8 ko1 = *(const bf16x8*)&Kb[(re + 4) * 64 + ((4 + q) ^ swk) * 8];
        const float4 be = *(const float4*)&biasv[b * 2048 + s0 + q * 8];
        const float4 bo = *(const float4*)&biasv[b * 2048 + s0 + q * 8 + 4];
        bf16x8 pfrag[2];
#pragma unroll
        for (int qg = 0; qg < 2; ++qg) {
            floatx4 te = fzero, to = fzero;
            te = __builtin_amdgcn_mfma_f32_16x16x32_bf16(ke0, qa[qg][0], te, 0, 0, 0);
            te = __builtin_amdgcn_mfma_f32_16x16x32_bf16(ke1, qa[qg][1], te, 0, 0, 0);
            to = __builtin_amdgcn_mfma_f32_16x16x32_bf16(ko0, qa[qg][0], to, 0, 0, 0);
            to = __builtin_amdgcn_mfma_f32_16x16x32_bf16(ko1, qa[qg][1], to, 0, 0, 0);
            float pe0 = fexp2(fmaf(te[0], KSC, be.x));
            float pe1 = fexp2(fmaf(te[1], KSC, be.y));
            float pe2 = fexp2(fmaf(te[2], KSC, be.z));
            float pe3 = fexp2(fmaf(te[3], KSC, be.w));
            float po0 = fexp2(fmaf(to[0], KSC, bo.x));
            float po1 = fexp2(fmaf(to[1], KSC, bo.y));
            float po2 = fexp2(fmaf(to[2], KSC, bo.z));
            float po3 = fexp2(fmaf(to[3], KSC, bo.w));
            lsum[qg] += ((pe0 + pe1) + (pe2 + pe3)) + ((po0 + po1) + (po2 + po3));
            u32 pk[4];
            pk[0] = ((__builtin_bit_cast(u32, pe0) + 0x8000u) >> 16)
                  | ((__builtin_bit_cast(u32, pe1) + 0x8000u) & 0xffff0000u);
            pk[1] = ((__builtin_bit_cast(u32, pe2) + 0x8000u) >> 16)
                  | ((__builtin_bit_cast(u32, pe3) + 0x8000u) & 0xffff0000u);
            pk[2] = ((__builtin_bit_cast(u32, po0) + 0x8000u) >> 16)
                  | ((__builtin_bit_cast(u32, po1) + 0x8000u) & 0xffff0000u);
            pk[3] = ((__builtin_bit_cast(u32, po2) + 0x8000u) >> 16)
                  | ((__builtin_bit_cast(u32, po3) + 0x8000u) & 0xffff0000u);
            pfrag[qg] = __builtin_bit_cast(bf16x8, *(uint4*)pk);
        }
#pragma unroll
        for (int dt = 0; dt < 4; ++dt) {
            int vrow = dt * 16 + ml;
            bf16x8 vf = *(const bf16x8*)&Vb[vrow * 32 + ((q ^ ((vrow >> 1) & 3)) * 8)];
#pragma unroll
            for (int qg = 0; qg < 2; ++qg)
                oacc[qg][dt] = __builtin_amdgcn_mfma_f32_16x16x32_bf16(
                    vf, pfrag[qg], oacc[qg][dt], 0, 0, 0);
        }
    }

    // cross-half combine via LDS (fp32): waves kv=1 dump, waves kv=0 reduce
    __syncthreads();
    float* sO = (float*)&Ks[0][0][0];   // 16 KB: [qw*2+qg][dt][lane*4+r]
    float* sL = (float*)&Vs[0][0][0];   // 1 KB
    if (kv == 1) {
#pragma unroll
        for (int qg = 0; qg < 2; ++qg) {
            sL[(qw * 2 + qg) * 64 + lane] = lsum[qg];
#pragma unroll
            for (int dt = 0; dt < 4; ++dt)
                *(floatx4*)&sO[((qw * 2 + qg) * 4 + dt) * 256 + lane * 4] = oacc[qg][dt];
        }
    }
    __syncthreads();
    if (kv == 1) return;
#pragma unroll
    for (int qg = 0; qg < 2; ++qg) {
        lsum[qg] += sL[(qw * 2 + qg) * 64 + lane];
#pragma unroll
        for (int dt = 0; dt < 4; ++dt)
            oacc[qg][dt] += *(const floatx4*)&sO[((qw * 2 + qg) * 4 + dt) * 256 + lane * 4];
        float ls = lsum[qg];
        ls += __shfl_xor(ls, 16, 64);
        ls += __shfl_xor(ls, 32, 64);
        const float rcp = 1.f / ls;
        const size_t row = rowQ + qw * 32 + qg * 16 + ml;
#pragma unroll
        for (int dt = 0; dt < 4; ++dt)
#pragma unroll
            for (int rp = 0; rp < 4; rp += 2) {
                u32 pk = (u32)f2bf(oacc[qg][dt][rp] * rcp)
                       | ((u32)f2bf(oacc[qg][dt][rp + 1] * rcp) << 16);
                *(u32*)&O[row * 1024 + h * 64 + dt * 16 + q * 4 + rp] = pk;
            }
    }
}

// V [b*2048+s][h*64+d] -> Vt [b*1024+h*64+d][s], 64x64 tiles via LDS
__global__ __launch_bounds__(256) void vtrans(const u16* __restrict__ Vb, u16* __restrict__ Vt)
{
    __shared__ __align__(16) u16 T[64 * 72];
    const int tid = threadIdx.x;
    const int ct = blockIdx.x, rt = blockIdx.y;
    const int b = rt >> 5;
    const int s0 = (rt & 31) * 64;
    const int c0 = ct * 64;
#pragma unroll
    for (int p = 0; p < 2; ++p) {
        int slot = p * 256 + tid;
        int lr = slot >> 3, pc = slot & 7;
        bf16x8 v = *(const bf16x8*)&Vb[(size_t)(b * 2048 + s0 + lr) * 1024 + c0 + pc * 8];
        *(bf16x8*)&T[lr * 72 + pc * 8] = v;
    }
    __syncthreads();
#pragma unroll
    for (int p = 0; p < 2; ++p) {
        int slot = p * 256 + tid;
        int dc = slot >> 3, sc0 = (slot & 7) * 8;
        ushort8v o;
#pragma unroll
        for (int j = 0; j < 8; ++j) o[j] = T[(sc0 + j) * 72 + dc];
        *(ushort8v*)&Vt[(size_t)(b * 1024 + c0 + dc) * 2048 + s0 + sc0] = o;
    }
}

// LayerNorm (torch semantics: ddof=1 variance, eps added to std), fp32 -> bf16
DEVI void ln_row(const float* __restrict__ x, float ga, float gb,
                 u16* __restrict__ y, int row, int tid)
{
    const float4 v = ((const float4*)(x + (size_t)row * 1024))[tid];
    float s = v.x + v.y + v.z + v.w;
    float ss = v.x * v.x + v.y * v.y + v.z * v.z + v.w * v.w;
#pragma unroll
    for (int d = 1; d < 64; d <<= 1) { s += __shfl_xor(s, d, 64); ss += __shfl_xor(ss, d, 64); }
    __shared__ float ps[4], pss[4];
    const int w = tid >> 6, lane = tid & 63;
    if (lane == 0) { ps[w] = s; pss[w] = ss; }
    __syncthreads();
    s = ps[0] + ps[1] + ps[2] + ps[3];
    ss = pss[0] + pss[1] + pss[2] + pss[3];
    float mean = s * (1.f / 1024.f);
    float var = fmaxf((ss - s * mean) * (1.f / 1023.f), 0.f);
    float sc = ga / (sqrtf(var) + 1e-6f);
    ushort4v o;
    o[0] = f2bf((v.x - mean) * sc + gb);
    o[1] = f2bf((v.y - mean) * sc + gb);
    o[2] = f2bf((v.z - mean) * sc + gb);
    o[3] = f2bf((v.w - mean) * sc + gb);
    ((ushort4v*)(y + (size_t)row * 1024))[tid] = o;
}

__global__ __launch_bounds__(256) void ln_bf16(const float* __restrict__ x,
    const float* __restrict__ ga, const float* __restrict__ gb, u16* __restrict__ y)
{
    ln_row(x, ga[0], gb[0], y, blockIdx.x, threadIdx.x);
}

// prep: weight casts (blocks 0..12287) + mask bias (12288..12303) + LN1 (12304..16399)
__global__ __launch_bounds__(256) void prep(
    const float* __restrict__ wq, const float* __restrict__ wk,
    const float* __restrict__ wv, const float* __restrict__ wo,
    const float* __restrict__ w1, const float* __restrict__ w2,
    u16* __restrict__ wqb, u16* __restrict__ wkb, u16* __restrict__ wvb,
    u16* __restrict__ wob, u16* __restrict__ w1b, u16* __restrict__ w2b,
    const int* __restrict__ m, float* __restrict__ biasv,
    const float* __restrict__ src, const float* __restrict__ a1,
    const float* __restrict__ be1, u16* __restrict__ xln1)
{
    const int bx = blockIdx.x;
    if (bx < 12288) {
        size_t i = (size_t)bx * 256 + threadIdx.x;   // float4 index
        const float* s; u16* d; size_t off;
        if (i < 262144)       { s = wq; d = wqb; off = i; }
        else if (i < 524288)  { s = wk; d = wkb; off = i - 262144; }
        else if (i < 786432)  { s = wv; d = wvb; off = i - 524288; }
        else if (i < 1048576) { s = wo; d = wob; off = i - 786432; }
        else if (i < 2097152) { s = w1; d = w1b; off = i - 1048576; }
        else                  { s = w2; d = w2b; off = i - 2097152; }
        float4 v = ((const float4*)s)[off];
        ushort4v o = {f2bf(v.x), f2bf(v.y), f2bf(v.z), f2bf(v.w)};
        ((ushort4v*)d)[off] = o;
    } else if (bx < 12304) {
        int i = (bx - 12288) * 256 + threadIdx.x;
        biasv[i] = m[i] ? 0.f : -1.442695e9f;
    } else {
        ln_row(src, a1[0], be1[0], xln1, bx - 12304, threadIdx.x);
    }
}

// FF2 finish: out = (bf16 partials P0+P1) + b2[col] + resid
__global__ __launch_bounds__(256) void ff2_fin(
    const u16* __restrict__ p0, const u16* __restrict__ p1,
    const float* __restrict__ b2, const float* __restrict__ resid,
    float* __restrict__ out)
{
    const size_t i = (size_t)blockIdx.x * 256 + threadIdx.x;   // float4 index
    ushort4v a = *(const ushort4v*)&p0[i * 4];
    ushort4v b = *(const ushort4v*)&p1[i * 4];
    float4 r = ((const float4*)resid)[i];
    float4 bb = ((const float4*)b2)[i & 255];
    float4 o;
    o.x = (bf2f(a[0]) + bf2f(b[0])) + r.x + bb.x;
    o.y = (bf2f(a[1]) + bf2f(b[1])) + r.y + bb.y;
    o.z = (bf2f(a[2]) + bf2f(b[2])) + r.z + bb.z;
    o.w = (bf2f(a[3]) + bf2f(b[3])) + r.w + bb.w;
    ((float4*)out)[i] = o;
}

extern "C" void kernel_launch(void* const* d_in, const int* in_sizes, int n_in,
                              void* d_out, int out_size, void* d_ws, size_t ws_size,
                              hipStream_t stream)
{
    const float* src = (const float*)d_in[0];
    const int* msk   = (const int*)d_in[1];
    const float* wq  = (const float*)d_in[2];
    const float* wk  = (const float*)d_in[3];
    const float* wv  = (const float*)d_in[4];
    const float* wo  = (const float*)d_in[5];
    const float* w1  = (const float*)d_in[6];
    const float* b1  = (const float*)d_in[7];
    const float* w2  = (const float*)d_in[8];
    const float* b2  = (const float*)d_in[9];
    const float* a1  = (const float*)d_in[10];
    const float* be1 = (const float*)d_in[11];
    const float* a2  = (const float*)d_in[12];
    const float* be2 = (const float*)d_in[13];
    float* out = (float*)d_out;

    char* ws = (char*)d_ws;
    const size_t MB = (size_t)1 << 20;
    u16* wqb  = (u16*)(ws + 0 * MB);
    u16* wkb  = (u16*)(ws + 2 * MB);
    u16* wvb  = (u16*)(ws + 4 * MB);
    u16* wob  = (u16*)(ws + 6 * MB);
    u16* w1b  = (u16*)(ws + 8 * MB);    // 8..16
    u16* w2b  = (u16*)(ws + 16 * MB);   // 16..24 (live through FF2)
    u16* xln1 = (u16*)(ws + 24 * MB);   // 24..32; dead after QKV; aliased by attn
    u16* attn = xln1;
    u16* Qb   = (u16*)(ws + 32 * MB);   // 32..40; dead after flash; aliased by xln2
    u16* xln2 = Qb;
    u16* Kb   = (u16*)(ws + 40 * MB);   // 40..48
    u16* Vb   = (u16*)(ws + 48 * MB);   // 48..56
    u16* Vt   = (u16*)(ws + 56 * MB);   // 56..64
    float* biasv = (float*)(ws + 64 * MB);  // 16 KB in 64..72 spare
    u16* h1   = (u16*)(ws + 40 * MB);   // 32 MB: 40..72 (Kb/Vb/Vt dead by then)
    float* src2 = (float*)(ws + 72 * MB); // 16 MB: 72..88
    // FF2 bf16 partials in dead regions (weights 0..8 dead, attn 24..32 dead):
    u16* P0 = (u16*)(ws + 0 * MB);
    u16* P1 = (u16*)(ws + 24 * MB);

    // fused: weight casts + mask bias + LN1
    prep<<<16400, 256, 0, stream>>>(wq, wk, wv, wo, w1, w2,
                                    wqb, wkb, wvb, wob, w1b, w2b,
                                    msk, biasv, src, a1, be1, xln1);

    // fused QKV: N_total=3072, per-block weight/output select
    gemm_nt<128, 128, 2, 2, true, 1, true, false, false, false, true><<<dim3(24, 32), 256, 0, stream>>>(
        xln1, wqb, wkb, wvb, nullptr, nullptr, Qb, Kb, Vb, nullptr, 1024, 1024, 1024, 0);

    vtrans<<<dim3(16, 64), 256, 0, stream>>>(Vb, Vt);

    flash8<<<dim3(32, 32), 256, 0, stream>>>(Qb, Kb, Vt, biasv, attn);

    // O-projection + residual (fp32)
    gemm_nt<128, 64, 4, 1, false, 1, true, false, false, true, false><<<dim3(16, 32), 256, 0, stream>>>(
        attn, wob, nullptr, nullptr, nullptr, src, src2, nullptr, nullptr, nullptr,
        1024, 1024, 1024, 0);

    ln_bf16<<<4096, 256, 0, stream>>>(src2, a2, be2, xln2);

    // FF1: bias + ReLU -> bf16
    gemm_nt<128, 128, 2, 2, false, 1, true, true, true, false, true><<<dim3(32, 32), 256, 0, stream>>>(
        xln2, w1b, nullptr, nullptr, b1, nullptr, h1, nullptr, nullptr, nullptr,
        1024, 1024, 4096, 0);

    // FF2: split-K=2 (R8-proven shape) into bf16 partials
    gemm_nt<128, 128, 2, 2, false, 2, true, false, false, false, true><<<dim3(16, 32), 256, 0, stream>>>(
        h1, w2b, nullptr, nullptr, nullptr, nullptr, P0, P1, nullptr, nullptr,
        2048, 4096, 1024, 8);

    // out = P0+P1 + b2 + src2
    ff2_fin<<<4096, 256, 0, stream>>>(P0, P1, b2, src2, out);
}

// Round 2
// 334.680 us; speedup vs baseline: 1.0690x; 1.0690x over previous
//
#include <hip/hip_runtime.h>
#include <hip/hip_bf16.h>

typedef unsigned short u16;
typedef unsigned int u32;
typedef float floatx4 __attribute__((ext_vector_type(4)));
typedef __bf16 bf16x8 __attribute__((ext_vector_type(8)));
typedef u16 ushort4v __attribute__((ext_vector_type(4)));
typedef u16 ushort8v __attribute__((ext_vector_type(8)));

#define DEVI static __device__ __forceinline__

DEVI u16 f2bf(float f) {
    u32 u = __builtin_bit_cast(u32, f);
    u += 0x7fffu + ((u >> 16) & 1u);   // round-to-nearest-even
    return (u16)(u >> 16);
}
DEVI float bf2f(u16 h) { return __builtin_bit_cast(float, (u32)h << 16); }

DEVI float fexp2(float x) { return __builtin_amdgcn_exp2f(x); }  // v_exp_f32

// packed f32->bf16 convert (RTNE), one VALU op for two values
DEVI u32 cvtpk_bf16(float lo, float hi) {
    u32 r;
    asm("v_cvt_pk_bf16_f32 %0, %1, %2" : "=v"(r) : "v"(lo), "v"(hi));
    return r;
}

// async global->LDS, 16B per lane. dst must be wave-uniform base; HW adds lane*16.
DEVI void async_cp16(const u16* g, u16* l) {
    __builtin_amdgcn_global_load_lds((const __attribute__((address_space(1))) u32*)g,
                                     (__attribute__((address_space(3))) u32*)l, 16, 0, 0);
}

// ---------------------------------------------------------------------------
// GEMM: C[M,N] = A[M,K](bf16) @ W[N,K](bf16)^T, double-buffered one-barrier
// K-loop, async global_load_lds staging with XOR swizzle.
// XSWZ: XCD m-band block swizzle. NSPLIT>1: split-K partials to o0..o3.
// VTW (with QKV3): sel==2 (V) blocks write transposed directly to o3 as
// Vt[(b*1024 + n)*2048 + s] (replaces the vtrans kernel; 4 consecutive s
// per lane -> 8B stores).
// ---------------------------------------------------------------------------
template<int BM, int BN, int RW, int CW, bool QKV3, int NSPLIT, bool XSWZ,
         bool BIAS, bool RELU, bool RESID, bool OBF16, bool VTW>
__global__ __launch_bounds__(256) void gemm_nt(
    const u16* __restrict__ A,
    const u16* __restrict__ W0, const u16* __restrict__ W1, const u16* __restrict__ W2,
    const float* __restrict__ bias, const float* __restrict__ resid,
    void* __restrict__ o0, void* __restrict__ o1, void* __restrict__ o2,
    void* __restrict__ o3, int K, int lda, int Nper, int NX)
{
    static_assert(RW * CW == 4, "4 waves");
    constexpr int WM = BM / RW, WN = BN / CW;
    constexpr int MI = WM / 16, NI = WN / 16;
    __shared__ __align__(16) u16 As[2][BM * 32];
    __shared__ __align__(16) u16 Bs[2][BN * 32];
    const int tid = threadIdx.x;
    const int w = tid >> 6, lane = tid & 63;
    const int q = lane >> 4, ml = lane & 15;
    const int wr = w / CW, wc = w % CW;
    int bx = blockIdx.x, by = blockIdx.y;
    if (XSWZ) {
        const int gx = gridDim.x, gy = gridDim.y;
        int L = by * gx + bx;
        int xcd = L & 7, s = L >> 3;
        int mb = gy >> 3;              // m-tiles per XCD band (gy % 8 == 0)
        by = xcd * mb + s % mb;
        bx = s / mb;
    }
    const int m0 = by * BM;
    size_t kbase = 0;
    const u16* W = W0;
    void* outp = o0;
    if (NSPLIT > 1) {
        int part = bx / NX; bx -= part * NX; kbase = (size_t)part * K;
        outp = (part == 0) ? o0 : (part == 1 ? o1 : (part == 2 ? o2 : o3));
    }
    int n0 = bx * BN;
    bool vwrite = false;
    if (QKV3) {
        int sel = n0 / Nper;
        n0 -= sel * Nper;
        W = (sel == 0) ? W0 : (sel == 1 ? W1 : W2);
        outp = (sel == 0) ? o0 : (sel == 1 ? o1 : o2);
        if (VTW) vwrite = (sel == 2);
    }

    auto stage = [&](int buf, int kt) {
#pragma unroll
        for (int p = 0; p < BM / 64; ++p) {
            int g = p * 256 + tid;
            int r = g >> 2, s = g & 3;
            int c = s ^ ((r >> 1) & 3);
            async_cp16(A + (size_t)(m0 + r) * lda + kbase + kt + c * 8,
                       &As[buf][(p * 256 + w * 64) * 8]);
        }
#pragma unroll
        for (int p = 0; p < BN / 64; ++p) {
            int g = p * 256 + tid;
            int r = g >> 2, s = g & 3;
            int c = s ^ ((r >> 1) & 3);
            async_cp16(W + (size_t)(n0 + r) * lda + kbase + kt + c * 8,
                       &Bs[buf][(p * 256 + w * 64) * 8]);
        }
    };

    const floatx4 fzero = {0.f, 0.f, 0.f, 0.f};
    floatx4 acc[MI][NI];
#pragma unroll
    for (int i = 0; i < MI; ++i)
#pragma unroll
        for (int j = 0; j < NI; ++j) acc[i][j] = fzero;

    stage(0, 0);
    for (int it = 0, kt = 0; kt < K; ++it, kt += 32) {
        __syncthreads();
        if (kt + 32 < K) stage((it + 1) & 1, kt + 32);
        const u16* Asb = As[it & 1];
        const u16* Bsb = Bs[it & 1];
        bf16x8 af[MI], bfr[NI];
#pragma unroll
        for (int i = 0; i < MI; ++i) {
            int rm = wr * WM + i * 16 + ml;
            int s = q ^ ((rm >> 1) & 3);
            af[i] = *(const bf16x8*)&Asb[(rm * 4 + s) * 8];
        }
#pragma unroll
        for (int j = 0; j < NI; ++j) {
            int rn = wc * WN + j * 16 + ml;
            int s = q ^ ((rn >> 1) & 3);
            bfr[j] = *(const bf16x8*)&Bsb[(rn * 4 + s) * 8];
        }
#pragma unroll
        for (int i = 0; i < MI; ++i)
#pragma unroll
            for (int j = 0; j < NI; ++j)
                acc[i][j] = __builtin_amdgcn_mfma_f32_16x16x32_bf16(af[i], bfr[j], acc[i][j], 0, 0, 0);
    }

    // epilogue: C/D layout col=lane&15, row=(lane>>4)*4+reg
#pragma unroll
    for (int j = 0; j < NI; ++j) {
        int gn = n0 + wc * WN + j * 16 + ml;
        float bj = 0.f;
        if (BIAS) bj = bias[gn];
#pragma unroll
        for (int i = 0; i < MI; ++i) {
            int gm0 = m0 + wr * WM + i * 16 + q * 4;
            if (VTW && vwrite) {
                // transposed V write: rows gn of Vt, cols gm0..gm0+3 (contig)
                int bb = gm0 >> 11, sres = gm0 & 2047;
                ushort4v o = {f2bf(acc[i][j][0]), f2bf(acc[i][j][1]),
                              f2bf(acc[i][j][2]), f2bf(acc[i][j][3])};
                *(ushort4v*)&((u16*)o3)[(size_t)(bb * 1024 + gn) * 2048 + sres] = o;
            } else {
#pragma unroll
                for (int r = 0; r < 4; ++r) {
                    size_t idx = (size_t)(gm0 + r) * Nper + gn;
                    float v = acc[i][j][r] + bj;
                    if (RELU) v = fmaxf(v, 0.f);
                    if (RESID) v += resid[idx];
                    if (OBF16) ((u16*)outp)[idx] = f2bf(v);
                    else       ((float*)outp)[idx] = v;
                }
            }
        }
    }
}

// ---------------------------------------------------------------------------
// Flash attention v9: counted-vmcnt 2-deep pipeline + 64 queries/wave.
// 256 threads = 4 waves: qw = w&1 selects 64-query half (block covers 128 q
// rows), kv = w>>1 selects KV half [kv*1024, kv*1024+1024). Grid (16,32).
// 3 LDS buffers per (K,V,half); stage(it+2) issued each iter; raw s_barrier
// with asm vmcnt(4) so the next tile's 4 loads stay in flight (T3/T4).
// biasv loads pinned BEFORE stage so their compiler wait is vmcnt(4), not 0.
// Tail stages clamp to tile 31 (harmless dup) to keep waitcnt counts static.
// Softmax pack via v_cvt_pk_bf16_f32. Partials combined through LDS in fp32.
// Q,K: [b*2048+s][h*64+d].  Vt: [b*1024+h*64+d][s].
// ---------------------------------------------------------------------------
__global__ __launch_bounds__(256, 2) void flash9(
    const u16* __restrict__ Q, const u16* __restrict__ Kg,
    const u16* __restrict__ Vt, const float* __restrict__ biasv,
    u16* __restrict__ O)
{
    // 48 KB: Ks [hf][buf] 32x64 at (hf*3+buf)*2048; Vs same shape at +12288
    __shared__ __align__(16) u16 smem[24576];
    const int tid = threadIdx.x;
    const int w = tid >> 6, lane = tid & 63;
    const int qw = w & 1, kv = w >> 1;
    const int q = lane >> 4, ml = lane & 15;
    const int b = blockIdx.y >> 4, h = blockIdx.y & 15;
    const size_t rowQ = (size_t)(b * 2048 + blockIdx.x * 128);
    const float KSC = 0.125f * 1.4426950408889634f;   // /sqrt(64) * log2(e)
    const floatx4 fzero = {0.f, 0.f, 0.f, 0.f};

    bf16x8 qa[4][2];
#pragma unroll
    for (int qg = 0; qg < 4; ++qg)
#pragma unroll
        for (int c = 0; c < 2; ++c)
            qa[qg][c] = *(const bf16x8*)&Q[(rowQ + qw * 64 + qg * 16 + ml) * 1024
                                           + h * 64 + q * 8 + c * 32];

    // stage K/V 32-row tiles for BOTH kv halves: 4 loads/thread = 16KB/iter
    auto stage = [&](int buf, int it) {
        {   // K: 32 rows x 64 d, 8 chunks/row
            int row = tid >> 3, sl = tid & 7;
            int ch = sl ^ ((row & 3) | (((row >> 3) & 1) << 2));
#pragma unroll
            for (int hf = 0; hf < 2; ++hf)
                async_cp16(Kg + (size_t)(b * 2048 + hf * 1024 + it * 32 + row) * 1024
                               + h * 64 + ch * 8,
                           &smem[(hf * 3 + buf) * 2048 + w * 512]);
        }
        {   // V: 64 d-rows x 32 s, 4 chunks/row
            int row = tid >> 2, sl = tid & 3;
            int ch = sl ^ ((row >> 1) & 3);
#pragma unroll
            for (int hf = 0; hf < 2; ++hf)
                async_cp16(Vt + (size_t)(b * 1024 + h * 64 + row) * 2048
                               + hf * 1024 + it * 32 + ch * 8,
                           &smem[12288 + (hf * 3 + buf) * 2048 + w * 512]);
        }
    };

    floatx4 oacc[4][4];
    float lsum[4] = {0.f, 0.f, 0.f, 0.f};
#pragma unroll
    for (int qg = 0; qg < 4; ++qg)
#pragma unroll
        for (int d = 0; d < 4; ++d) oacc[qg][d] = fzero;

    const int swk = (ml & 3) | (((ml >> 2) & 1) << 2);
    const int re = ((ml >> 2) << 3) + (ml & 3);   // even K-rows (key relabel)

    stage(0, 0);
    stage(1, 1);
    int cb = 0, nb = 2;
    for (int it = 0; it < 32; ++it) {
        // loads(it) were drained by the biasv wait in body(it-1); the next
        // tile's 4 loads stay in flight across this barrier.
        asm volatile("s_waitcnt vmcnt(4)" ::: "memory");
        __builtin_amdgcn_s_barrier();
        __builtin_amdgcn_sched_barrier(0);
        const int s0 = kv * 1024 + it * 32;
        const float4 be = *(const float4*)&biasv[b * 2048 + s0 + q * 8];
        const float4 bo = *(const float4*)&biasv[b * 2048 + s0 + q * 8 + 4];
        __builtin_amdgcn_sched_barrier(0);   // keep biasv issued before stage
        stage(nb, it + 2 < 32 ? it + 2 : 31);   // unconditional: static waits

        const u16* Kb = &smem[(kv * 3 + cb) * 2048];
        const u16* Vb = &smem[12288 + (kv * 3 + cb) * 2048];

        bf16x8 ke0 = *(const bf16x8*)&Kb[(re + 0) * 64 + ((0 + q) ^ swk) * 8];
        bf16x8 ke1 = *(const bf16x8*)&Kb[(re + 0) * 64 + ((4 + q) ^ swk) * 8];
        bf16x8 ko0 = *(const bf16x8*)&Kb[(re + 4) * 64 + ((0 + q) ^ swk) * 8];
        bf16x8 ko1 = *(const bf16x8*)&Kb[(re + 4) * 64 + ((4 + q) ^ swk) * 8];
        bf16x8 pfrag[4];
#pragma unroll
        for (int qg = 0; qg < 4; ++qg) {
            floatx4 te = fzero, to = fzero;
            te = __builtin_amdgcn_mfma_f32_16x16x32_bf16(ke0, qa[qg][0], te, 0, 0, 0);
            te = __builtin_amdgcn_mfma_f32_16x16x32_bf16(ke1, qa[qg][1], te, 0, 0, 0);
            to = __builtin_amdgcn_mfma_f32_16x16x32_bf16(ko0, qa[qg][0], to, 0, 0, 0);
            to = __builtin_amdgcn_mfma_f32_16x16x32_bf16(ko1, qa[qg][1], to, 0, 0, 0);
            float pe0 = fexp2(fmaf(te[0], KSC, be.x));
            float pe1 = fexp2(fmaf(te[1], KSC, be.y));
            float pe2 = fexp2(fmaf(te[2], KSC, be.z));
            float pe3 = fexp2(fmaf(te[3], KSC, be.w));
            float po0 = fexp2(fmaf(to[0], KSC, bo.x));
            float po1 = fexp2(fmaf(to[1], KSC, bo.y));
            float po2 = fexp2(fmaf(to[2], KSC, bo.z));
            float po3 = fexp2(fmaf(to[3], KSC, bo.w));
            lsum[qg] += ((pe0 + pe1) + (pe2 + pe3)) + ((po0 + po1) + (po2 + po3));
            u32 pk[4];
            pk[0] = cvtpk_bf16(pe0, pe1);
            pk[1] = cvtpk_bf16(pe2, pe3);
            pk[2] = cvtpk_bf16(po0, po1);
            pk[3] = cvtpk_bf16(po2, po3);
            pfrag[qg] = __builtin_bit_cast(bf16x8, *(uint4*)pk);
        }
#pragma unroll
        for (int dt = 0; dt < 4; ++dt) {
            int vrow = dt * 16 + ml;
            bf16x8 vf = *(const bf16x8*)&Vb[vrow * 32 + ((q ^ ((vrow >> 1) & 3)) * 8)];
#pragma unroll
            for (int qg = 0; qg < 4; ++qg)
                oacc[qg][dt] = __builtin_amdgcn_mfma_f32_16x16x32_bf16(
                    vf, pfrag[qg], oacc[qg][dt], 0, 0, 0);
        }
        cb = cb == 2 ? 0 : cb + 1;
        nb = nb == 2 ? 0 : nb + 1;
    }

    // cross-half combine via LDS (fp32): waves kv=1 dump, waves kv=0 reduce
    __syncthreads();
    float* sO = (float*)smem;          // 32 KB: [(qw*4+qg)*4+dt][lane*4+r]
    float* sL = (float*)smem + 8192;   // 2 KB
    if (kv == 1) {
#pragma unroll
        for (int qg = 0; qg < 4; ++qg) {
            sL[(qw * 4 + qg) * 64 + lane] = lsum[qg];
#pragma unroll
            for (int dt = 0; dt < 4; ++dt)
                *(floatx4*)&sO[((qw * 4 + qg) * 4 + dt) * 256 + lane * 4] = oacc[qg][dt];
        }
    }
    __syncthreads();
    if (kv == 1) return;
#pragma unroll
    for (int qg = 0; qg < 4; ++qg) {
        lsum[qg] += sL[(qw * 4 + qg) * 64 + lane];
#pragma unroll
        for (int dt = 0; dt < 4; ++dt)
            oacc[qg][dt] += *(const floatx4*)&sO[((qw * 4 + qg) * 4 + dt) * 256 + lane * 4];
        float ls = lsum[qg];
        ls += __shfl_xor(ls, 16, 64);
        ls += __shfl_xor(ls, 32, 64);
        const float rcp = 1.f / ls;
        const size_t row = rowQ + qw * 64 + qg * 16 + ml;
#pragma unroll
        for (int dt = 0; dt < 4; ++dt)
#pragma unroll
            for (int rp = 0; rp < 4; rp += 2) {
                u32 pk = (u32)f2bf(oacc[qg][dt][rp] * rcp)
                       | ((u32)f2bf(oacc[qg][dt][rp + 1] * rcp) << 16);
                *(u32*)&O[row * 1024 + h * 64 + dt * 16 + q * 4 + rp] = pk;
            }
    }
}

// LayerNorm (torch semantics: ddof=1 variance, eps added to std), fp32 -> bf16
DEVI void ln_row(const float* __restrict__ x, float ga, float gb,
                 u16* __restrict__ y, int row, int tid)
{
    const float4 v = ((const float4*)(x + (size_t)row * 1024))[tid];
    float s = v.x + v.y + v.z + v.w;
    float ss = v.x * v.x + v.y * v.y + v.z * v.z + v.w * v.w;
#pragma unroll
    for (int d = 1; d < 64; d <<= 1) { s += __shfl_xor(s, d, 64); ss += __shfl_xor(ss, d, 64); }
    __shared__ float ps[4], pss[4];
    const int w = tid >> 6, lane = tid & 63;
    if (lane == 0) { ps[w] = s; pss[w] = ss; }
    __syncthreads();
    s = ps[0] + ps[1] + ps[2] + ps[3];
    ss = pss[0] + pss[1] + pss[2] + pss[3];
    float mean = s * (1.f / 1024.f);
    float var = fmaxf((ss - s * mean) * (1.f / 1023.f), 0.f);
    float sc = ga / (sqrtf(var) + 1e-6f);
    ushort4v o;
    o[0] = f2bf((v.x - mean) * sc + gb);
    o[1] = f2bf((v.y - mean) * sc + gb);
    o[2] = f2bf((v.z - mean) * sc + gb);
    o[3] = f2bf((v.w - mean) * sc + gb);
    ((ushort4v*)(y + (size_t)row * 1024))[tid] = o;
}

__global__ __launch_bounds__(256) void ln_bf16(const float* __restrict__ x,
    const float* __restrict__ ga, const float* __restrict__ gb, u16* __restrict__ y)
{
    ln_row(x, ga[0], gb[0], y, blockIdx.x, threadIdx.x);
}

// prep: weight casts (blocks 0..12287) + mask bias (12288..12303) + LN1 (12304..16399)
__global__ __launch_bounds__(256) void prep(
    const float* __restrict__ wq, const float* __restrict__ wk,
    const float* __restrict__ wv, const float* __restrict__ wo,
    const float* __restrict__ w1, const float* __restrict__ w2,
    u16* __restrict__ wqb, u16* __restrict__ wkb, u16* __restrict__ wvb,
    u16* __restrict__ wob, u16* __restrict__ w1b, u16* __restrict__ w2b,
    const int* __restrict__ m, float* __restrict__ biasv,
    const float* __restrict__ src, const float* __restrict__ a1,
    const float* __restrict__ be1, u16* __restrict__ xln1)
{
    const int bx = blockIdx.x;
    if (bx < 12288) {
        size_t i = (size_t)bx * 256 + threadIdx.x;   // float4 index
        const float* s; u16* d; size_t off;
        if (i < 262144)       { s = wq; d = wqb; off = i; }
        else if (i < 524288)  { s = wk; d = wkb; off = i - 262144; }
        else if (i < 786432)  { s = wv; d = wvb; off = i - 524288; }
        else if (i < 1048576) { s = wo; d = wob; off = i - 786432; }
        else if (i < 2097152) { s = w1; d = w1b; off = i - 1048576; }
        else                  { s = w2; d = w2b; off = i - 2097152; }
        float4 v = ((const float4*)s)[off];
        ushort4v o = {f2bf(v.x), f2bf(v.y), f2bf(v.z), f2bf(v.w)};
        ((ushort4v*)d)[off] = o;
    } else if (bx < 12304) {
        int i = (bx - 12288) * 256 + threadIdx.x;
        biasv[i] = m[i] ? 0.f : -1.442695e9f;
    } else {
        ln_row(src, a1[0], be1[0], xln1, bx - 12304, threadIdx.x);
    }
}

// FF2 finish: out = (bf16 partials P0+P1) + b2[col] + resid
__global__ __launch_bounds__(256) void ff2_fin(
    const u16* __restrict__ p0, const u16* __restrict__ p1,
    const float* __restrict__ b2, const float* __restrict__ resid,
    float* __restrict__ out)
{
    const size_t i = (size_t)blockIdx.x * 256 + threadIdx.x;   // float4 index
    ushort4v a = *(const ushort4v*)&p0[i * 4];
    ushort4v b = *(const ushort4v*)&p1[i * 4];
    float4 r = ((const float4*)resid)[i];
    float4 bb = ((const float4*)b2)[i & 255];
    float4 o;
    o.x = (bf2f(a[0]) + bf2f(b[0])) + r.x + bb.x;
    o.y = (bf2f(a[1]) + bf2f(b[1])) + r.y + bb.y;
    o.z = (bf2f(a[2]) + bf2f(b[2])) + r.z + bb.z;
    o.w = (bf2f(a[3]) + bf2f(b[3])) + r.w + bb.w;
    ((float4*)out)[i] = o;
}

extern "C" void kernel_launch(void* const* d_in, const int* in_sizes, int n_in,
                              void* d_out, int out_size, void* d_ws, size_t ws_size,
                              hipStream_t stream)
{
    const float* src = (const float*)d_in[0];
    const int* msk   = (const int*)d_in[1];
    const float* wq  = (const float*)d_in[2];
    const float* wk  = (const float*)d_in[3];
    const float* wv  = (const float*)d_in[4];
    const float* wo  = (const float*)d_in[5];
    const float* w1  = (const float*)d_in[6];
    const float* b1  = (const float*)d_in[7];
    const float* w2  = (const float*)d_in[8];
    const float* b2  = (const float*)d_in[9];
    const float* a1  = (const float*)d_in[10];
    const float* be1 = (const float*)d_in[11];
    const float* a2  = (const float*)d_in[12];
    const float* be2 = (const float*)d_in[13];
    float* out = (float*)d_out;

    char* ws = (char*)d_ws;
    const size_t MB = (size_t)1 << 20;
    u16* wqb  = (u16*)(ws + 0 * MB);
    u16* wkb  = (u16*)(ws + 2 * MB);
    u16* wvb  = (u16*)(ws + 4 * MB);
    u16* wob  = (u16*)(ws + 6 * MB);
    u16* w1b  = (u16*)(ws + 8 * MB);    // 8..16
    u16* w2b  = (u16*)(ws + 16 * MB);   // 16..24 (live through FF2)
    u16* xln1 = (u16*)(ws + 24 * MB);   // 24..32; dead after QKV; aliased by attn
    u16* attn = xln1;
    u16* Qb   = (u16*)(ws + 32 * MB);   // 32..40; dead after flash; aliased by xln2
    u16* xln2 = Qb;
    u16* Kb   = (u16*)(ws + 40 * MB);   // 40..48
    u16* Vt   = (u16*)(ws + 56 * MB);   // 56..64 (written directly by QKV VTW)
    float* biasv = (float*)(ws + 64 * MB);  // 16 KB in 64..72 spare
    u16* h1   = (u16*)(ws + 40 * MB);   // 32 MB: 40..72 (Kb/Vt dead by then)
    float* src2 = (float*)(ws + 72 * MB); // 16 MB: 72..88
    // FF2 bf16 partials in dead regions (weights 0..8 dead, attn 24..32 dead):
    u16* P0 = (u16*)(ws + 0 * MB);
    u16* P1 = (u16*)(ws + 24 * MB);

    // fused: weight casts + mask bias + LN1
    prep<<<16400, 256, 0, stream>>>(wq, wk, wv, wo, w1, w2,
                                    wqb, wkb, wvb, wob, w1b, w2b,
                                    msk, biasv, src, a1, be1, xln1);

    // fused QKV: N_total=3072, per-block weight/output select; V written
    // transposed directly to Vt (o3) -- vtrans kernel eliminated.
    gemm_nt<128, 128, 2, 2, true, 1, true, false, false, false, true, true><<<dim3(24, 32), 256, 0, stream>>>(
        xln1, wqb, wkb, wvb, nullptr, nullptr, Qb, Kb, nullptr, Vt, 1024, 1024, 1024, 0);

    flash9<<<dim3(16, 32), 256, 0, stream>>>(Qb, Kb, Vt, biasv, attn);

    // O-projection + residual (fp32)
    gemm_nt<128, 64, 4, 1, false, 1, true, false, false, true, false, false><<<dim3(16, 32), 256, 0, stream>>>(
        attn, wob, nullptr, nullptr, nullptr, src, src2, nullptr, nullptr, nullptr,
        1024, 1024, 1024, 0);

    ln_bf16<<<4096, 256, 0, stream>>>(src2, a2, be2, xln2);

    // FF1: bias + ReLU -> bf16
    gemm_nt<128, 128, 2, 2, false, 1, true, true, true, false, true, false><<<dim3(32, 32), 256, 0, stream>>>(
        xln2, w1b, nullptr, nullptr, b1, nullptr, h1, nullptr, nullptr, nullptr,
        1024, 1024, 4096, 0);

    // FF2: split-K=2 (R8-proven shape) into bf16 partials
    gemm_nt<128, 128, 2, 2, false, 2, true, false, false, false, true, false><<<dim3(16, 32), 256, 0, stream>>>(
        h1, w2b, nullptr, nullptr, nullptr, nullptr, P0, P1, nullptr, nullptr,
        2048, 4096, 1024, 8);

    // out = P0+P1 + b2 + src2
    ff2_fin<<<4096, 256, 0, stream>>>(P0, P1, b2, src2, out);
}

// Round 3
// 334.082 us; speedup vs baseline: 1.0709x; 1.0018x over previous
//
#include <hip/hip_runtime.h>
#include <hip/hip_bf16.h>

typedef unsigned short u16;
typedef unsigned int u32;
typedef float floatx4 __attribute__((ext_vector_type(4)));
typedef __bf16 bf16x8 __attribute__((ext_vector_type(8)));
typedef u16 ushort4v __attribute__((ext_vector_type(4)));
typedef u16 ushort8v __attribute__((ext_vector_type(8)));

#define DEVI static __device__ __forceinline__

DEVI u16 f2bf(float f) {
    u32 u = __builtin_bit_cast(u32, f);
    u += 0x7fffu + ((u >> 16) & 1u);   // round-to-nearest-even
    return (u16)(u >> 16);
}
DEVI float bf2f(u16 h) { return __builtin_bit_cast(float, (u32)h << 16); }

DEVI float fexp2(float x) { return __builtin_amdgcn_exp2f(x); }  // v_exp_f32

// packed f32->bf16 convert (RTNE), one VALU op for two values
DEVI u32 cvtpk_bf16(float lo, float hi) {
    u32 r;
    asm("v_cvt_pk_bf16_f32 %0, %1, %2" : "=v"(r) : "v"(lo), "v"(hi));
    return r;
}

// async global->LDS, 16B per lane. dst must be wave-uniform base; HW adds lane*16.
DEVI void async_cp16(const u16* g, u16* l) {
    __builtin_amdgcn_global_load_lds((const __attribute__((address_space(1))) u32*)g,
                                     (__attribute__((address_space(3))) u32*)l, 16, 0, 0);
}

template<int N> DEVI void wait_vmcnt() {
    if constexpr (N == 2)      asm volatile("s_waitcnt vmcnt(2)" ::: "memory");
    else if constexpr (N == 3) asm volatile("s_waitcnt vmcnt(3)" ::: "memory");
    else if constexpr (N == 4) asm volatile("s_waitcnt vmcnt(4)" ::: "memory");
    else if constexpr (N == 6) asm volatile("s_waitcnt vmcnt(6)" ::: "memory");
    else if constexpr (N == 8) asm volatile("s_waitcnt vmcnt(8)" ::: "memory");
    else static_assert(N == 2, "add vmcnt case");
}

// ---------------------------------------------------------------------------
// GEMM: C[M,N] = A[M,K](bf16) @ W[N,K](bf16)^T.
// Counted-vmcnt 2-deep pipeline (flash9-proven): 3 LDS buffers, raw s_barrier
// preceded by s_waitcnt vmcnt(LPT) so the NEXT tile's staging loads stay in
// flight across the barrier (never drain to 0 in the loop).
// XSWZ: XCD m-band block swizzle. NSPLIT>1: split-K partials to o0..o3.
// VTW (with QKV3): sel==2 (V) blocks write transposed directly to o3 as
// Vt[(b*1024 + n)*2048 + s] (4 consecutive s per lane -> 8B stores).
// ---------------------------------------------------------------------------
template<int BM, int BN, int RW, int CW, bool QKV3, int NSPLIT, bool XSWZ,
         bool BIAS, bool RELU, bool RESID, bool OBF16, bool VTW>
__global__ __launch_bounds__(256) void gemm_nt(
    const u16* __restrict__ A,
    const u16* __restrict__ W0, const u16* __restrict__ W1, const u16* __restrict__ W2,
    const float* __restrict__ bias, const float* __restrict__ resid,
    void* __restrict__ o0, void* __restrict__ o1, void* __restrict__ o2,
    void* __restrict__ o3, int K, int lda, int Nper, int NX)
{
    static_assert(RW * CW == 4, "4 waves");
    constexpr int WM = BM / RW, WN = BN / CW;
    constexpr int MI = WM / 16, NI = WN / 16;
    constexpr int LPT = BM / 64 + BN / 64;   // staging loads per thread per tile
    __shared__ __align__(16) u16 As[3][BM * 32];
    __shared__ __align__(16) u16 Bs[3][BN * 32];
    const int tid = threadIdx.x;
    const int w = tid >> 6, lane = tid & 63;
    const int q = lane >> 4, ml = lane & 15;
    const int wr = w / CW, wc = w % CW;
    int bx = blockIdx.x, by = blockIdx.y;
    if (XSWZ) {
        const int gx = gridDim.x, gy = gridDim.y;
        int L = by * gx + bx;
        int xcd = L & 7, s = L >> 3;
        int mb = gy >> 3;              // m-tiles per XCD band (gy % 8 == 0)
        by = xcd * mb + s % mb;
        bx = s / mb;
    }
    const int m0 = by * BM;
    size_t kbase = 0;
    const u16* W = W0;
    void* outp = o0;
    if (NSPLIT > 1) {
        int part = bx / NX; bx -= part * NX; kbase = (size_t)part * K;
        outp = (part == 0) ? o0 : (part == 1 ? o1 : (part == 2 ? o2 : o3));
    }
    int n0 = bx * BN;
    bool vwrite = false;
    if (QKV3) {
        int sel = n0 / Nper;
        n0 -= sel * Nper;
        W = (sel == 0) ? W0 : (sel == 1 ? W1 : W2);
        outp = (sel == 0) ? o0 : (sel == 1 ? o1 : o2);
        if (VTW) vwrite = (sel == 2);
    }

    auto stage = [&](int buf, int kt) {
#pragma unroll
        for (int p = 0; p < BM / 64; ++p) {
            int g = p * 256 + tid;
            int r = g >> 2, s = g & 3;
            int c = s ^ ((r >> 1) & 3);
            async_cp16(A + (size_t)(m0 + r) * lda + kbase + kt + c * 8,
                       &As[buf][(p * 256 + w * 64) * 8]);
        }
#pragma unroll
        for (int p = 0; p < BN / 64; ++p) {
            int g = p * 256 + tid;
            int r = g >> 2, s = g & 3;
            int c = s ^ ((r >> 1) & 3);
            async_cp16(W + (size_t)(n0 + r) * lda + kbase + kt + c * 8,
                       &Bs[buf][(p * 256 + w * 64) * 8]);
        }
    };

    const floatx4 fzero = {0.f, 0.f, 0.f, 0.f};
    floatx4 acc[MI][NI];
#pragma unroll
    for (int i = 0; i < MI; ++i)
#pragma unroll
        for (int j = 0; j < NI; ++j) acc[i][j] = fzero;

    const int nt = K >> 5;
    stage(0, 0);
    stage(1, 32);
    int cb = 0, nb = 2;
    for (int it = 0, kt = 0; it < nt; ++it, kt += 32) {
        // drain only tile it's LPT loads; tile it+1's stay in flight
        wait_vmcnt<LPT>();
        __builtin_amdgcn_s_barrier();
        __builtin_amdgcn_sched_barrier(0);
        if (it + 2 < nt) stage(nb, kt + 64);
        __builtin_amdgcn_sched_barrier(0);
        const u16* Asb = As[cb];
        const u16* Bsb = Bs[cb];
        bf16x8 af[MI], bfr[NI];
#pragma unroll
        for (int i = 0; i < MI; ++i) {
            int rm = wr * WM + i * 16 + ml;
            int s = q ^ ((rm >> 1) & 3);
            af[i] = *(const bf16x8*)&Asb[(rm * 4 + s) * 8];
        }
#pragma unroll
        for (int j = 0; j < NI; ++j) {
            int rn = wc * WN + j * 16 + ml;
            int s = q ^ ((rn >> 1) & 3);
            bfr[j] = *(const bf16x8*)&Bsb[(rn * 4 + s) * 8];
        }
#pragma unroll
        for (int i = 0; i < MI; ++i)
#pragma unroll
            for (int j = 0; j < NI; ++j)
                acc[i][j] = __builtin_amdgcn_mfma_f32_16x16x32_bf16(af[i], bfr[j], acc[i][j], 0, 0, 0);
        cb = cb == 2 ? 0 : cb + 1;
        nb = nb == 2 ? 0 : nb + 1;
    }

    // epilogue: C/D layout col=lane&15, row=(lane>>4)*4+reg
#pragma unroll
    for (int j = 0; j < NI; ++j) {
        int gn = n0 + wc * WN + j * 16 + ml;
        float bj = 0.f;
        if (BIAS) bj = bias[gn];
#pragma unroll
        for (int i = 0; i < MI; ++i) {
            int gm0 = m0 + wr * WM + i * 16 + q * 4;
            if (VTW && vwrite) {
                // transposed V write: rows gn of Vt, cols gm0..gm0+3 (contig)
                int bb = gm0 >> 11, sres = gm0 & 2047;
                ushort4v o = {f2bf(acc[i][j][0]), f2bf(acc[i][j][1]),
                              f2bf(acc[i][j][2]), f2bf(acc[i][j][3])};
                *(ushort4v*)&((u16*)o3)[(size_t)(bb * 1024 + gn) * 2048 + sres] = o;
            } else {
#pragma unroll
                for (int r = 0; r < 4; ++r) {
                    size_t idx = (size_t)(gm0 + r) * Nper + gn;
                    float v = acc[i][j][r] + bj;
                    if (RELU) v = fmaxf(v, 0.f);
                    if (RESID) v += resid[idx];
                    if (OBF16) ((u16*)outp)[idx] = f2bf(v);
                    else       ((float*)outp)[idx] = v;
                }
            }
        }
    }
}

// ---------------------------------------------------------------------------
// Flash attention v9 (R1 winner, unchanged): counted-vmcnt 2-deep pipeline +
// 64 queries/wave. 256 threads = 4 waves: qw = w&1 selects 64-query half,
// kv = w>>1 selects KV half. Grid (16,32). 3 LDS buffers per (K,V,half).
// Q,K: [b*2048+s][h*64+d].  Vt: [b*1024+h*64+d][s].
// ---------------------------------------------------------------------------
__global__ __launch_bounds__(256, 2) void flash9(
    const u16* __restrict__ Q, const u16* __restrict__ Kg,
    const u16* __restrict__ Vt, const float* __restrict__ biasv,
    u16* __restrict__ O)
{
    // 48 KB: Ks [hf][buf] 32x64 at (hf*3+buf)*2048; Vs same shape at +12288
    __shared__ __align__(16) u16 smem[24576];
    const int tid = threadIdx.x;
    const int w = tid >> 6, lane = tid & 63;
    const int qw = w & 1, kv = w >> 1;
    const int q = lane >> 4, ml = lane & 15;
    const int b = blockIdx.y >> 4, h = blockIdx.y & 15;
    const size_t rowQ = (size_t)(b * 2048 + blockIdx.x * 128);
    const float KSC = 0.125f * 1.4426950408889634f;   // /sqrt(64) * log2(e)
    const floatx4 fzero = {0.f, 0.f, 0.f, 0.f};

    bf16x8 qa[4][2];
#pragma unroll
    for (int qg = 0; qg < 4; ++qg)
#pragma unroll
        for (int c = 0; c < 2; ++c)
            qa[qg][c] = *(const bf16x8*)&Q[(rowQ + qw * 64 + qg * 16 + ml) * 1024
                                           + h * 64 + q * 8 + c * 32];

    // stage K/V 32-row tiles for BOTH kv halves: 4 loads/thread = 16KB/iter
    auto stage = [&](int buf, int it) {
        {   // K: 32 rows x 64 d, 8 chunks/row
            int row = tid >> 3, sl = tid & 7;
            int ch = sl ^ ((row & 3) | (((row >> 3) & 1) << 2));
#pragma unroll
            for (int hf = 0; hf < 2; ++hf)
                async_cp16(Kg + (size_t)(b * 2048 + hf * 1024 + it * 32 + row) * 1024
                               + h * 64 + ch * 8,
                           &smem[(hf * 3 + buf) * 2048 + w * 512]);
        }
        {   // V: 64 d-rows x 32 s, 4 chunks/row
            int row = tid >> 2, sl = tid & 3;
            int ch = sl ^ ((row >> 1) & 3);
#pragma unroll
            for (int hf = 0; hf < 2; ++hf)
                async_cp16(Vt + (size_t)(b * 1024 + h * 64 + row) * 2048
                               + hf * 1024 + it * 32 + ch * 8,
                           &smem[12288 + (hf * 3 + buf) * 2048 + w * 512]);
        }
    };

    floatx4 oacc[4][4];
    float lsum[4] = {0.f, 0.f, 0.f, 0.f};
#pragma unroll
    for (int qg = 0; qg < 4; ++qg)
#pragma unroll
        for (int d = 0; d < 4; ++d) oacc[qg][d] = fzero;

    const int swk = (ml & 3) | (((ml >> 2) & 1) << 2);
    const int re = ((ml >> 2) << 3) + (ml & 3);   // even K-rows (key relabel)

    stage(0, 0);
    stage(1, 1);
    int cb = 0, nb = 2;
    for (int it = 0; it < 32; ++it) {
        asm volatile("s_waitcnt vmcnt(4)" ::: "memory");
        __builtin_amdgcn_s_barrier();
        __builtin_amdgcn_sched_barrier(0);
        const int s0 = kv * 1024 + it * 32;
        const float4 be = *(const float4*)&biasv[b * 2048 + s0 + q * 8];
        const float4 bo = *(const float4*)&biasv[b * 2048 + s0 + q * 8 + 4];
        __builtin_amdgcn_sched_barrier(0);   // keep biasv issued before stage
        stage(nb, it + 2 < 32 ? it + 2 : 31);   // unconditional: static waits

        const u16* Kb = &smem[(kv * 3 + cb) * 2048];
        const u16* Vb = &smem[12288 + (kv * 3 + cb) * 2048];

        bf16x8 ke0 = *(const bf16x8*)&Kb[(re + 0) * 64 + ((0 + q) ^ swk) * 8];
        bf16x8 ke1 = *(const bf16x8*)&Kb[(re + 0) * 64 + ((4 + q) ^ swk) * 8];
        bf16x8 ko0 = *(const bf16x8*)&Kb[(re + 4) * 64 + ((0 + q) ^ swk) * 8];
        bf16x8 ko1 = *(const bf16x8*)&Kb[(re + 4) * 64 + ((4 + q) ^ swk) * 8];
        bf16x8 pfrag[4];
#pragma unroll
        for (int qg = 0; qg < 4; ++qg) {
            floatx4 te = fzero, to = fzero;
            te = __builtin_amdgcn_mfma_f32_16x16x32_bf16(ke0, qa[qg][0], te, 0, 0, 0);
            te = __builtin_amdgcn_mfma_f32_16x16x32_bf16(ke1, qa[qg][1], te, 0, 0, 0);
            to = __builtin_amdgcn_mfma_f32_16x16x32_bf16(ko0, qa[qg][0], to, 0, 0, 0);
            to = __builtin_amdgcn_mfma_f32_16x16x32_bf16(ko1, qa[qg][1], to, 0, 0, 0);
            float pe0 = fexp2(fmaf(te[0], KSC, be.x));
            float pe1 = fexp2(fmaf(te[1], KSC, be.y));
            float pe2 = fexp2(fmaf(te[2], KSC, be.z));
            float pe3 = fexp2(fmaf(te[3], KSC, be.w));
            float po0 = fexp2(fmaf(to[0], KSC, bo.x));
            float po1 = fexp2(fmaf(to[1], KSC, bo.y));
            float po2 = fexp2(fmaf(to[2], KSC, bo.z));
            float po3 = fexp2(fmaf(to[3], KSC, bo.w));
            lsum[qg] += ((pe0 + pe1) + (pe2 + pe3)) + ((po0 + po1) + (po2 + po3));
            u32 pk[4];
            pk[0] = cvtpk_bf16(pe0, pe1);
            pk[1] = cvtpk_bf16(pe2, pe3);
            pk[2] = cvtpk_bf16(po0, po1);
            pk[3] = cvtpk_bf16(po2, po3);
            pfrag[qg] = __builtin_bit_cast(bf16x8, *(uint4*)pk);
        }
#pragma unroll
        for (int dt = 0; dt < 4; ++dt) {
            int vrow = dt * 16 + ml;
            bf16x8 vf = *(const bf16x8*)&Vb[vrow * 32 + ((q ^ ((vrow >> 1) & 3)) * 8)];
#pragma unroll
            for (int qg = 0; qg < 4; ++qg)
                oacc[qg][dt] = __builtin_amdgcn_mfma_f32_16x16x32_bf16(
                    vf, pfrag[qg], oacc[qg][dt], 0, 0, 0);
        }
        cb = cb == 2 ? 0 : cb + 1;
        nb = nb == 2 ? 0 : nb + 1;
    }

    // cross-half combine via LDS (fp32): waves kv=1 dump, waves kv=0 reduce
    __syncthreads();
    float* sO = (float*)smem;          // 32 KB: [(qw*4+qg)*4+dt][lane*4+r]
    float* sL = (float*)smem + 8192;   // 2 KB
    if (kv == 1) {
#pragma unroll
        for (int qg = 0; qg < 4; ++qg) {
            sL[(qw * 4 + qg) * 64 + lane] = lsum[qg];
#pragma unroll
            for (int dt = 0; dt < 4; ++dt)
                *(floatx4*)&sO[((qw * 4 + qg) * 4 + dt) * 256 + lane * 4] = oacc[qg][dt];
        }
    }
    __syncthreads();
    if (kv == 1) return;
#pragma unroll
    for (int qg = 0; qg < 4; ++qg) {
        lsum[qg] += sL[(qw * 4 + qg) * 64 + lane];
#pragma unroll
        for (int dt = 0; dt < 4; ++dt)
            oacc[qg][dt] += *(const floatx4*)&sO[((qw * 4 + qg) * 4 + dt) * 256 + lane * 4];
        float ls = lsum[qg];
        ls += __shfl_xor(ls, 16, 64);
        ls += __shfl_xor(ls, 32, 64);
        const float rcp = 1.f / ls;
        const size_t row = rowQ + qw * 64 + qg * 16 + ml;
#pragma unroll
        for (int dt = 0; dt < 4; ++dt)
#pragma unroll
            for (int rp = 0; rp < 4; rp += 2) {
                u32 pk = (u32)f2bf(oacc[qg][dt][rp] * rcp)
                       | ((u32)f2bf(oacc[qg][dt][rp + 1] * rcp) << 16);
                *(u32*)&O[row * 1024 + h * 64 + dt * 16 + q * 4 + rp] = pk;
            }
    }
}

// LayerNorm (torch semantics: ddof=1 variance, eps added to std), fp32 -> bf16
DEVI void ln_row(const float* __restrict__ x, float ga, float gb,
                 u16* __restrict__ y, int row, int tid)
{
    const float4 v = ((const float4*)(x + (size_t)row * 1024))[tid];
    float s = v.x + v.y + v.z + v.w;
    float ss = v.x * v.x + v.y * v.y + v.z * v.z + v.w * v.w;
#pragma unroll
    for (int d = 1; d < 64; d <<= 1) { s += __shfl_xor(s, d, 64); ss += __shfl_xor(ss, d, 64); }
    __shared__ float ps[4], pss[4];
    const int w = tid >> 6, lane = tid & 63;
    if (lane == 0) { ps[w] = s; pss[w] = ss; }
    __syncthreads();
    s = ps[0] + ps[1] + ps[2] + ps[3];
    ss = pss[0] + pss[1] + pss[2] + pss[3];
    float mean = s * (1.f / 1024.f);
    float var = fmaxf((ss - s * mean) * (1.f / 1023.f), 0.f);
    float sc = ga / (sqrtf(var) + 1e-6f);
    ushort4v o;
    o[0] = f2bf((v.x - mean) * sc + gb);
    o[1] = f2bf((v.y - mean) * sc + gb);
    o[2] = f2bf((v.z - mean) * sc + gb);
    o[3] = f2bf((v.w - mean) * sc + gb);
    ((ushort4v*)(y + (size_t)row * 1024))[tid] = o;
}

__global__ __launch_bounds__(256) void ln_bf16(const float* __restrict__ x,
    const float* __restrict__ ga, const float* __restrict__ gb, u16* __restrict__ y)
{
    ln_row(x, ga[0], gb[0], y, blockIdx.x, threadIdx.x);
}

// prep: weight casts (blocks 0..12287) + mask bias (12288..12303) + LN1 (12304..16399)
__global__ __launch_bounds__(256) void prep(
    const float* __restrict__ wq, const float* __restrict__ wk,
    const float* __restrict__ wv, const float* __restrict__ wo,
    const float* __restrict__ w1, const float* __restrict__ w2,
    u16* __restrict__ wqb, u16* __restrict__ wkb, u16* __restrict__ wvb,
    u16* __restrict__ wob, u16* __restrict__ w1b, u16* __restrict__ w2b,
    const int* __restrict__ m, float* __restrict__ biasv,
    const float* __restrict__ src, const float* __restrict__ a1,
    const float* __restrict__ be1, u16* __restrict__ xln1)
{
    const int bx = blockIdx.x;
    if (bx < 12288) {
        size_t i = (size_t)bx * 256 + threadIdx.x;   // float4 index
        const float* s; u16* d; size_t off;
        if (i < 262144)       { s = wq; d = wqb; off = i; }
        else if (i < 524288)  { s = wk; d = wkb; off = i - 262144; }
        else if (i < 786432)  { s = wv; d = wvb; off = i - 524288; }
        else if (i < 1048576) { s = wo; d = wob; off = i - 786432; }
        else if (i < 2097152) { s = w1; d = w1b; off = i - 1048576; }
        else                  { s = w2; d = w2b; off = i - 2097152; }
        float4 v = ((const float4*)s)[off];
        ushort4v o = {f2bf(v.x), f2bf(v.y), f2bf(v.z), f2bf(v.w)};
        ((ushort4v*)d)[off] = o;
    } else if (bx < 12304) {
        int i = (bx - 12288) * 256 + threadIdx.x;
        biasv[i] = m[i] ? 0.f : -1.442695e9f;
    } else {
        ln_row(src, a1[0], be1[0], xln1, bx - 12304, threadIdx.x);
    }
}

// FF2 finish: out = (bf16 partials P0+P1) + b2[col] + resid
__global__ __launch_bounds__(256) void ff2_fin(
    const u16* __restrict__ p0, const u16* __restrict__ p1,
    const float* __restrict__ b2, const float* __restrict__ resid,
    float* __restrict__ out)
{
    const size_t i = (size_t)blockIdx.x * 256 + threadIdx.x;   // float4 index
    ushort4v a = *(const ushort4v*)&p0[i * 4];
    ushort4v b = *(const ushort4v*)&p1[i * 4];
    float4 r = ((const float4*)resid)[i];
    float4 bb = ((const float4*)b2)[i & 255];
    float4 o;
    o.x = (bf2f(a[0]) + bf2f(b[0])) + r.x + bb.x;
    o.y = (bf2f(a[1]) + bf2f(b[1])) + r.y + bb.y;
    o.z = (bf2f(a[2]) + bf2f(b[2])) + r.z + bb.z;
    o.w = (bf2f(a[3]) + bf2f(b[3])) + r.w + bb.w;
    ((float4*)out)[i] = o;
}

extern "C" void kernel_launch(void* const* d_in, const int* in_sizes, int n_in,
                              void* d_out, int out_size, void* d_ws, size_t ws_size,
                              hipStream_t stream)
{
    const float* src = (const float*)d_in[0];
    const int* msk   = (const int*)d_in[1];
    const float* wq  = (const float*)d_in[2];
    const float* wk  = (const float*)d_in[3];
    const float* wv  = (const float*)d_in[4];
    const float* wo  = (const float*)d_in[5];
    const float* w1  = (const float*)d_in[6];
    const float* b1  = (const float*)d_in[7];
    const float* w2  = (const float*)d_in[8];
    const float* b2  = (const float*)d_in[9];
    const float* a1  = (const float*)d_in[10];
    const float* be1 = (const float*)d_in[11];
    const float* a2  = (const float*)d_in[12];
    const float* be2 = (const float*)d_in[13];
    float* out = (float*)d_out;

    char* ws = (char*)d_ws;
    const size_t MB = (size_t)1 << 20;
    u16* wqb  = (u16*)(ws + 0 * MB);
    u16* wkb  = (u16*)(ws + 2 * MB);
    u16* wvb  = (u16*)(ws + 4 * MB);
    u16* wob  = (u16*)(ws + 6 * MB);
    u16* w1b  = (u16*)(ws + 8 * MB);    // 8..16
    u16* w2b  = (u16*)(ws + 16 * MB);   // 16..24 (live through FF2)
    u16* xln1 = (u16*)(ws + 24 * MB);   // 24..32; dead after QKV; aliased by attn
    u16* attn = xln1;
    u16* Qb   = (u16*)(ws + 32 * MB);   // 32..40; dead after flash; aliased by xln2
    u16* xln2 = Qb;
    u16* Kb   = (u16*)(ws + 40 * MB);   // 40..48
    u16* Vt   = (u16*)(ws + 56 * MB);   // 56..64 (written directly by QKV VTW)
    float* biasv = (float*)(ws + 64 * MB);  // 16 KB in 64..72 spare
    u16* h1   = (u16*)(ws + 40 * MB);   // 32 MB: 40..72 (Kb/Vt dead by then)
    float* src2 = (float*)(ws + 72 * MB); // 16 MB: 72..88
    // FF2 bf16 partials in dead regions (weights 0..8 dead, attn 24..32 dead):
    u16* P0 = (u16*)(ws + 0 * MB);
    u16* P1 = (u16*)(ws + 24 * MB);

    // fused: weight casts + mask bias + LN1
    prep<<<16400, 256, 0, stream>>>(wq, wk, wv, wo, w1, w2,
                                    wqb, wkb, wvb, wob, w1b, w2b,
                                    msk, biasv, src, a1, be1, xln1);

    // fused QKV: N_total=3072, per-block weight/output select; V written
    // transposed directly to Vt (o3) -- vtrans kernel eliminated.
    gemm_nt<128, 128, 2, 2, true, 1, true, false, false, false, true, true><<<dim3(24, 32), 256, 0, stream>>>(
        xln1, wqb, wkb, wvb, nullptr, nullptr, Qb, Kb, nullptr, Vt, 1024, 1024, 1024, 0);

    flash9<<<dim3(16, 32), 256, 0, stream>>>(Qb, Kb, Vt, biasv, attn);

    // O-projection + residual (fp32)
    gemm_nt<128, 64, 4, 1, false, 1, true, false, false, true, false, false><<<dim3(16, 32), 256, 0, stream>>>(
        attn, wob, nullptr, nullptr, nullptr, src, src2, nullptr, nullptr, nullptr,
        1024, 1024, 1024, 0);

    ln_bf16<<<4096, 256, 0, stream>>>(src2, a2, be2, xln2);

    // FF1: bias + ReLU -> bf16
    gemm_nt<128, 128, 2, 2, false, 1, true, true, true, false, true, false><<<dim3(32, 32), 256, 0, stream>>>(
        xln2, w1b, nullptr, nullptr, b1, nullptr, h1, nullptr, nullptr, nullptr,
        1024, 1024, 4096, 0);

    // FF2: split-K=2 (R8-proven shape) into bf16 partials
    gemm_nt<128, 128, 2, 2, false, 2, true, false, false, false, true, false><<<dim3(16, 32), 256, 0, stream>>>(
        h1, w2b, nullptr, nullptr, nullptr, nullptr, P0, P1, nullptr, nullptr,
        2048, 4096, 1024, 8);

    // out = P0+P1 + b2 + src2
    ff2_fin<<<4096, 256, 0, stream>>>(P0, P1, b2, src2, out);
}